// Round 10
// baseline (153.749 us; speedup 1.0000x reference)
//
#include <hip/hip_runtime.h>
#include <hip/hip_bf16.h>
#include <math.h>

#define B_   8
#define C_   32
#define H_   256
#define W_   256
#define HW_  (H_*W_)
#define NPIX (B_*C_*H_*W_)   // offset of logdet in d_out

// LDS: 2 staged rows x 34 px-slots x 32ch bf16; p = local col + 1.
// Halo cols p=0 (px0-1) and p=33 (px0+32). Same slot/swizzle formula as r9:
//   byte(r,p,g) = r*ROWB2 + p*64 + ((g ^ ((p>>2)&3)) << 4)   g = channel octet
#define SLOTS  34
#define ROWDW2 (SLOTS*16)      // 544 dwords per row
#define ROWB2  (ROWDW2*4)      // 2176 bytes per row

typedef __attribute__((ext_vector_type(8))) short short8;   // bf16x8 MFMA A/B frag
typedef __attribute__((ext_vector_type(4))) float f32x4;    // fp32x4 MFMA C/D frag
typedef __attribute__((ext_vector_type(2))) float f32x2;

static __device__ __forceinline__ short f2bf(float f) {
    union { __hip_bfloat16 h; short s; } u; u.h = __float2bfloat16(f); return u.s;
}
// pack two f32 -> bf16x2 dword (RNE), single HW instruction on gfx950
static __device__ __forceinline__ int cvtpk(float lo, float hi) {
    int r;
    asm("v_cvt_pk_bf16_f32 %0, %1, %2" : "=v"(r) : "v"(lo), "v"(hi));
    return r;
}

// ---------------------------------------------------------------------------
// Prep: weight-norm -> bf16 (RNE).
//   w1b[o*192 + tap*32 + c]                       (tap = kh*3+kw)
//   w2b[j*64 + slot]: hidden-dim permutation so conv2 B-frags are lane-local:
//     channel c (mt=c>>4, q=(c>>2)&3, reg=c&3) -> slot (mt>>1)*32+q*8+(mt&1)*4+reg
// ---------------------------------------------------------------------------
__global__ __launch_bounds__(64) void prep_kernel(
    const float* __restrict__ v1, const float* __restrict__ g1,
    const float* __restrict__ v2, const float* __restrict__ g2,
    short* __restrict__ w1b, short* __restrict__ w2b)
{
    const int t   = threadIdx.x;   // 0..63
    const int bid = blockIdx.x;    // 0..127
    if (bid < 64) {
        const int o = bid;
        float a0 = v1[o*192 + t];
        float a1 = v1[o*192 + t + 64];
        float a2 = v1[o*192 + t + 128];
        float s  = a0*a0 + a1*a1 + a2*a2;
        #pragma unroll
        for (int m = 32; m >= 1; m >>= 1) s += __shfl_xor(s, m, 64);
        const float inv = g1[o] / sqrtf(s);
        const int e0 = t, e1 = t + 64, e2 = t + 128;   // src idx = c*6 + tap
        w1b[o*192 + (e0%6)*32 + e0/6] = f2bf(a0*inv);
        w1b[o*192 + (e1%6)*32 + e1/6] = f2bf(a1*inv);
        w1b[o*192 + (e2%6)*32 + e2/6] = f2bf(a2*inv);
    } else {
        const int j = bid - 64;
        float a = v2[j*64 + t];
        float s = a*a;
        #pragma unroll
        for (int m = 32; m >= 1; m >>= 1) s += __shfl_xor(s, m, 64);
        const float inv = g2[j] / sqrtf(s);
        const int mt = t >> 4, r = t & 15;
        const int slot = (mt >> 1)*32 + ((r >> 2) << 3) + ((mt & 1) << 2) + (r & 3);
        w2b[j*64 + slot] = f2bf(a*inv);
    }
}

// ---------------------------------------------------------------------------
// Fused MFMA kernel: ONE WAVE per block, 32 px of one row per block.
// Grid = 8*256*8 = 16384 independent single-wave pipelines (r7's proven
// high-residency shape, minus its atomic poison).
// Two 16-px groups processed SEQUENTIALLY (#pragma unroll 1) so only
// acc1[4]+acc2[4] (32 regs) are live -> low VGPR -> high waves/SIMD.
// Weight/bias loads kept inside the loop via an opaque SGPR offset
// (defeats LICM/CSE register-pressure blowup); they are L1-hot.
// logdet: per-wave partial -> plain store (no atomics, r7 lesson).
// ---------------------------------------------------------------------------
__global__ __launch_bounds__(64) void flow_kernel(
    const float* __restrict__ x,
    const short* __restrict__ w1b, const short* __restrict__ w2b,
    const float* __restrict__ b1,  const float* __restrict__ b2,
    float* __restrict__ out, float* __restrict__ ldpart)
{
    __shared__ int ldsI[2*ROWDW2];   // 4352 B

    const int bi0  = blockIdx.x;          // 0..16383
    const int b    = bi0 & 7;             // image = XCD (round-robin dispatch)
    const int rest = bi0 >> 3;            // 0..2047
    const int h    = rest >> 3;           // output row
    const int px0  = (rest & 7) << 5;     // 32-px tile base

    const int l    = threadIdx.x;         // 0..63
    const int lrow = l & 15;
    const int q    = l >> 4;

    const float* xb = x + (size_t)b * (C_*HW_);
    float* ob       = out + (size_t)b * (C_*HW_);

    // ---- stage main 32 cols: lane = (hf = l>>5, r = (l>>4)&1, k = l&15) ----
    {
        const int hf = l >> 5;            // channel half (16 ch)
        const int r  = (l >> 4) & 1;      // staged row
        const int k  = l & 15;            // col pair
        const int hr = h - 2 + r;
        const int w0 = px0 + 2*k;
        const int p0 = 2*k + 1, p1 = 2*k + 2;
        const int sw0 = (p0 >> 2) & 3, sw1 = (p1 >> 2) & 3;
        const int g0 = hf*2, g1 = hf*2 + 1;
        int4 A0, B0, A1, B1;
        if (hr >= 0) {
            f32x2 a[16];
            const float* pr = xb + (size_t)(hf*16)*HW_ + (size_t)hr*W_ + w0;
            #pragma unroll
            for (int c = 0; c < 16; ++c)
                a[c] = *(const f32x2*)(pr + (size_t)c*HW_);
            A0.x = cvtpk(a[0][0],a[1][0]);  A0.y = cvtpk(a[2][0],a[3][0]);
            A0.z = cvtpk(a[4][0],a[5][0]);  A0.w = cvtpk(a[6][0],a[7][0]);
            B0.x = cvtpk(a[8][0],a[9][0]);  B0.y = cvtpk(a[10][0],a[11][0]);
            B0.z = cvtpk(a[12][0],a[13][0]);B0.w = cvtpk(a[14][0],a[15][0]);
            A1.x = cvtpk(a[0][1],a[1][1]);  A1.y = cvtpk(a[2][1],a[3][1]);
            A1.z = cvtpk(a[4][1],a[5][1]);  A1.w = cvtpk(a[6][1],a[7][1]);
            B1.x = cvtpk(a[8][1],a[9][1]);  B1.y = cvtpk(a[10][1],a[11][1]);
            B1.z = cvtpk(a[12][1],a[13][1]);B1.w = cvtpk(a[14][1],a[15][1]);
        } else {
            A0 = B0 = A1 = B1 = (int4){0,0,0,0};
        }
        *(int4*)((char*)ldsI + r*ROWB2 + p0*64 + ((g0 ^ sw0) << 4)) = A0;
        *(int4*)((char*)ldsI + r*ROWB2 + p0*64 + ((g1 ^ sw0) << 4)) = B0;
        *(int4*)((char*)ldsI + r*ROWB2 + p1*64 + ((g0 ^ sw1) << 4)) = A1;
        *(int4*)((char*)ldsI + r*ROWB2 + p1*64 + ((g1 ^ sw1) << 4)) = B1;
    }
    // ---- halo cols p=0 (px0-1), p=33 (px0+32); swz(0)=swz(33)=0 -----------
    {
        const int r  = l >> 5;
        const int hc = (l >> 4) & 1;
        const int c2 = l & 15;            // channel pair
        const int wc = hc ? (px0 + 32) : (px0 - 1);
        const int p  = hc ? 33 : 0;
        const int hr = h - 2 + r;
        int d = 0;
        if (hr >= 0 && wc >= 0 && wc < W_) {
            const float a0 = xb[(size_t)(2*c2  )*HW_ + (size_t)hr*W_ + wc];
            const float a1 = xb[(size_t)(2*c2+1)*HW_ + (size_t)hr*W_ + wc];
            d = cvtpk(a0, a1);
        }
        ldsI[r*ROWDW2 + p*16 + ((c2 >> 2) << 2) + (c2 & 3)] = d;
    }
    __syncthreads();   // single wave: just drains LDS writes

    // ---- two 16-px groups, sequential (register-narrow) --------------------
    float ldsum = 0.f;
    #pragma unroll 1
    for (int ntg = 0; ntg < 2; ++ntg) {
        // opaque zero offset: addresses become iteration-fresh so weight/bias
        // loads are NOT hoisted/CSE'd across iterations (register pressure).
        unsigned zoff = 0;
        asm volatile("" : "+s"(zoff));
        const short* w1p = w1b + zoff;
        const short* w2p = w2b + zoff;
        const float* b1p = b1 + zoff;
        const float* b2p = b2 + zoff;

        const int pxl = ntg*16 + lrow;       // local px 0..31

        // conv1: D1[o][px]
        f32x4 acc1[4];
        #pragma unroll
        for (int mt = 0; mt < 4; ++mt)
            acc1[mt] = *(const f32x4*)(b1p + mt*16 + 4*q);

        #pragma unroll
        for (int tap = 0; tap < 6; ++tap) {
            const int rb = (tap < 3) ? 0 : ROWB2;
            const int dw = (tap % 3) - 1;
            const int p  = pxl + dw + 1;
            const int byteoff = rb + p*64 + ((q ^ ((p >> 2) & 3)) << 4);
            const short8 xf = *(const short8*)((const char*)ldsI + byteoff);
            #pragma unroll
            for (int mt = 0; mt < 4; ++mt) {
                const short8 wf = *(const short8*)(w1p + (mt*16 + lrow)*192 + tap*32 + q*8);
                acc1[mt] = __builtin_amdgcn_mfma_f32_16x16x32_bf16(wf, xf, acc1[mt], 0, 0, 0);
            }
        }

        // ELU in-register
        #pragma unroll
        for (int mt = 0; mt < 4; ++mt)
            #pragma unroll
            for (int rg = 0; rg < 4; ++rg) {
                const float v = acc1[mt][rg];
                acc1[mt][rg] = v > 0.f ? v : (__expf(v) - 1.f);
            }

        // pack hidden acts (lane-local; hidden dim pre-permuted in w2b)
        union { int4 i; short8 s; } u0, u1;
        u0.i.x = cvtpk(acc1[0][0], acc1[0][1]);
        u0.i.y = cvtpk(acc1[0][2], acc1[0][3]);
        u0.i.z = cvtpk(acc1[1][0], acc1[1][1]);
        u0.i.w = cvtpk(acc1[1][2], acc1[1][3]);
        u1.i.x = cvtpk(acc1[2][0], acc1[2][1]);
        u1.i.y = cvtpk(acc1[2][2], acc1[2][3]);
        u1.i.z = cvtpk(acc1[3][0], acc1[3][1]);
        u1.i.w = cvtpk(acc1[3][2], acc1[3][3]);

        // conv2
        f32x4 acc2[4];
        #pragma unroll
        for (int mt2 = 0; mt2 < 4; ++mt2) {
            const short8 a0 = *(const short8*)(w2p + (mt2*16 + lrow)*64 +      q*8);
            const short8 a1 = *(const short8*)(w2p + (mt2*16 + lrow)*64 + 32 + q*8);
            f32x4 t0 = __builtin_amdgcn_mfma_f32_16x16x32_bf16(
                           a0, u0.s, (f32x4){0.f,0.f,0.f,0.f}, 0, 0, 0);
            acc2[mt2] = __builtin_amdgcn_mfma_f32_16x16x32_bf16(a1, u1.s, t0, 0, 0, 0);
        }

        // epilogue: sigmoid/affine/logdet, all lane-local
        const int colbase = h*W_ + px0 + pxl;
        float pr8 = 1.f;
        #pragma unroll
        for (int mt2 = 0; mt2 < 2; ++mt2) {
            const f32x4 bm = *(const f32x4*)(b2p + mt2*16 + 4*q);
            const f32x4 bs = *(const f32x4*)(b2p + 32 + mt2*16 + 4*q);
            #pragma unroll
            for (int rg = 0; rg < 4; ++rg) {
                const float mu = acc2[mt2][rg]     + bm[rg];
                const float z  = acc2[mt2 + 2][rg] + bs[rg] + 2.f;
                const float sc = 1.f / (1.f + __expf(-z));
                pr8 *= sc;
                const int j = mt2*16 + 4*q + rg;
                const size_t idx = (size_t)j * HW_ + colbase;
                ob[idx] = xb[idx] * sc + mu;
            }
        }
        ldsum += __logf(pr8);
    }

    // ---- logdet partial: wave reduce + plain store -------------------------
    #pragma unroll
    for (int m = 32; m >= 1; m >>= 1) ldsum += __shfl_xor(ldsum, m, 64);
    if (l == 0) ldpart[(size_t)b * 2048 + rest] = ldsum;
}

// ---------------------------------------------------------------------------
// Final reduce: 8 blocks, each sums 2048 partials -> logdet[b].
// ---------------------------------------------------------------------------
__global__ __launch_bounds__(256) void reduce_kernel(
    const float* __restrict__ ldpart, float* __restrict__ logdet)
{
    __shared__ float r4[4];
    const int b = blockIdx.x;
    const int t = threadIdx.x;
    const float* pp = ldpart + (size_t)b*2048 + t*8;
    const f32x4 v0 = *(const f32x4*)pp;
    const f32x4 v1 = *(const f32x4*)(pp + 4);
    float s = v0[0]+v0[1]+v0[2]+v0[3] + v1[0]+v1[1]+v1[2]+v1[3];
    #pragma unroll
    for (int m = 32; m >= 1; m >>= 1) s += __shfl_xor(s, m, 64);
    if ((t & 63) == 0) r4[t >> 6] = s;
    __syncthreads();
    if (t == 0) logdet[b] = r4[0] + r4[1] + r4[2] + r4[3];
}

// ---------------------------------------------------------------------------
extern "C" void kernel_launch(void* const* d_in, const int* in_sizes, int n_in,
                              void* d_out, int out_size, void* d_ws, size_t ws_size,
                              hipStream_t stream)
{
    const float* x  = (const float*)d_in[0];
    const float* v1 = (const float*)d_in[1];
    const float* g1 = (const float*)d_in[2];
    const float* b1 = (const float*)d_in[3];
    const float* v2 = (const float*)d_in[4];
    const float* g2 = (const float*)d_in[5];
    const float* b2 = (const float*)d_in[6];

    float* out    = (float*)d_out;
    float* logdet = out + NPIX;

    short* w1b    = (short*)d_ws;                    // 24576 B
    short* w2b    = w1b + 12288;                     //  8192 B
    float* ldpart = (float*)((char*)d_ws + 32768);   // 16384 f32 (64 KiB)

    prep_kernel<<<128, 64, 0, stream>>>(v1, g1, v2, g2, w1b, w2b);
    flow_kernel<<<B_ * H_ * 8, 64, 0, stream>>>(x, w1b, w2b, b1, b2, out, ldpart);
    reduce_kernel<<<B_, 256, 0, stream>>>(ldpart, logdet);
}

// Round 11
// 66.922 us; speedup vs baseline: 2.2975x; 2.2975x over previous
//
#include <hip/hip_runtime.h>
#include <hip/hip_bf16.h>
#include <math.h>

#define B_   8
#define C_   32
#define H_   256
#define W_   256
#define HW_  (H_*W_)
#define NPIX (B_*C_*H_*W_)   // offset of logdet in d_out

// LDS: 2 staged rows x 132 px-slots x 32ch bf16; p = local col + 1.
// Half-row tile: 128 px + halo cols p=0 and p=129 (130 used, 2 pad).
//   byte(r,p,g) = r*ROWB3 + p*64 + ((g ^ ((p>>2)&3)) << 4)   g = channel octet
#define SLOTS3  132
#define ROWDW3  (SLOTS3*16)     // 2112 dwords per row
#define ROWB3   (ROWDW3*4)      // 8448 bytes per row

typedef __attribute__((ext_vector_type(8))) short short8;   // bf16x8 MFMA A/B frag
typedef __attribute__((ext_vector_type(4))) float f32x4;    // fp32x4 MFMA C/D frag
typedef __attribute__((ext_vector_type(2))) float f32x2;

static __device__ __forceinline__ short f2bf(float f) {
    union { __hip_bfloat16 h; short s; } u; u.h = __float2bfloat16(f); return u.s;
}
// pack two f32 -> bf16x2 dword (RNE), single HW instruction on gfx950
static __device__ __forceinline__ int cvtpk(float lo, float hi) {
    int r;
    asm("v_cvt_pk_bf16_f32 %0, %1, %2" : "=v"(r) : "v"(lo), "v"(hi));
    return r;
}

// ---------------------------------------------------------------------------
// Prep: weight-norm -> bf16 (RNE).
//   w1b[o*192 + tap*32 + c]                       (tap = kh*3+kw)
//   w2b[j*64 + slot]: hidden-dim permutation so conv2 B-frags are lane-local:
//     channel c (mt=c>>4, q=(c>>2)&3, reg=c&3) -> slot (mt>>1)*32+q*8+(mt&1)*4+reg
// ---------------------------------------------------------------------------
__global__ __launch_bounds__(64) void prep_kernel(
    const float* __restrict__ v1, const float* __restrict__ g1,
    const float* __restrict__ v2, const float* __restrict__ g2,
    short* __restrict__ w1b, short* __restrict__ w2b)
{
    const int t   = threadIdx.x;   // 0..63
    const int bid = blockIdx.x;    // 0..127
    if (bid < 64) {
        const int o = bid;
        float a0 = v1[o*192 + t];
        float a1 = v1[o*192 + t + 64];
        float a2 = v1[o*192 + t + 128];
        float s  = a0*a0 + a1*a1 + a2*a2;
        #pragma unroll
        for (int m = 32; m >= 1; m >>= 1) s += __shfl_xor(s, m, 64);
        const float inv = g1[o] / sqrtf(s);
        const int e0 = t, e1 = t + 64, e2 = t + 128;   // src idx = c*6 + tap
        w1b[o*192 + (e0%6)*32 + e0/6] = f2bf(a0*inv);
        w1b[o*192 + (e1%6)*32 + e1/6] = f2bf(a1*inv);
        w1b[o*192 + (e2%6)*32 + e2/6] = f2bf(a2*inv);
    } else {
        const int j = bid - 64;
        float a = v2[j*64 + t];
        float s = a*a;
        #pragma unroll
        for (int m = 32; m >= 1; m >>= 1) s += __shfl_xor(s, m, 64);
        const float inv = g2[j] / sqrtf(s);
        const int mt = t >> 4, r = t & 15;
        const int slot = (mt >> 1)*32 + ((r >> 2) << 3) + ((mt & 1) << 2) + (r & 3);
        w2b[j*64 + slot] = f2bf(a*inv);
    }
}

// ---------------------------------------------------------------------------
// Fused MFMA kernel: one block per (b, h, half-row); 2 waves, 64 px each.
// Grid = 8*256*2 = 4096 blocks -> 8 blocks/CU static (VGPR-capped), 2x r9.
// ONE barrier (2 waves only): stage rows h-2,h-1 (halo'd) -> bar -> conv1 ->
// ELU -> conv2 -> epilogue.  Per-wave code identical to r9 (proven 65us core).
// conv1: D1[o][px] (A = weights, B = x-patch) -> lane holds o=4q+reg, px=lrow.
// conv2: lane-local B-frags (hidden dim pre-permuted in w2b).
// Staging: b128 LDS writes only (r8 lesson); cvtpk packing (r9 lesson);
// logdet: per-wave partial -> plain store (r7 lesson: no atomics).
// ---------------------------------------------------------------------------
__global__ __launch_bounds__(128) void flow_kernel(
    const float* __restrict__ x,
    const short* __restrict__ w1b, const short* __restrict__ w2b,
    const float* __restrict__ b1,  const float* __restrict__ b2,
    float* __restrict__ out, float* __restrict__ ldpart)
{
    __shared__ int ldsI[2*ROWDW3];   // 16896 B

    const int bi0  = blockIdx.x;           // 0..4095
    const int b    = bi0 & 7;              // image = XCD (round-robin dispatch)
    const int rest = bi0 >> 3;             // 0..511
    const int h    = rest >> 1;            // output row
    const int pxb  = (rest & 1) << 7;      // half-row base: 0 or 128

    const int tid  = threadIdx.x;          // 0..127
    const int l    = tid & 63;
    const int wv   = tid >> 6;             // 0/1
    const int lrow = l & 15;
    const int q    = l >> 4;

    const float* xb = x + (size_t)b * (C_*HW_);
    float* ob       = out + (size_t)b * (C_*HW_);

    // ---- stage rows h-2 (r=0), h-1 (r=1): 64 threads per row ---------------
    {
        const int r   = tid >> 6;          // staged row index
        const int hr  = h - 2 + r;
        const int k   = tid & 63;          // local px pair
        const int p0  = 2*k + 1, p1 = 2*k + 2;
        const int sw0 = (p0 >> 2) & 3, sw1 = (p1 >> 2) & 3;
        if (hr >= 0) {
            const float* pr = xb + (size_t)hr * W_ + (pxb + 2*k);
            #pragma unroll
            for (int g = 0; g < 4; ++g) {          // channel octet 8g..8g+7
                f32x2 a[8];
                #pragma unroll
                for (int j = 0; j < 8; ++j)
                    a[j] = *(const f32x2*)(pr + (size_t)(8*g + j) * HW_);
                int4 d0, d1;
                d0.x = cvtpk(a[0][0], a[1][0]); d0.y = cvtpk(a[2][0], a[3][0]);
                d0.z = cvtpk(a[4][0], a[5][0]); d0.w = cvtpk(a[6][0], a[7][0]);
                d1.x = cvtpk(a[0][1], a[1][1]); d1.y = cvtpk(a[2][1], a[3][1]);
                d1.z = cvtpk(a[4][1], a[5][1]); d1.w = cvtpk(a[6][1], a[7][1]);
                *(int4*)&ldsI[r*ROWDW3 + p0*16 + ((g ^ sw0) << 2)] = d0;
                *(int4*)&ldsI[r*ROWDW3 + p1*16 + ((g ^ sw1) << 2)] = d1;
            }
        } else {
            const int4 z4 = {0,0,0,0};
            #pragma unroll
            for (int g = 0; g < 4; ++g) {
                *(int4*)&ldsI[r*ROWDW3 + p0*16 + ((g ^ sw0) << 2)] = z4;
                *(int4*)&ldsI[r*ROWDW3 + p1*16 + ((g ^ sw1) << 2)] = z4;
            }
        }
        // halo cols p=0 (w=pxb-1) and p=129 (w=pxb+128); swz(0)=swz(129)=0,
        // so dword i <-> channel pair i (identity). 64 dwords total.
        if (tid < 64) {
            const int rz = tid >> 5;               // row
            const int hc = (tid >> 4) & 1;         // which halo col
            const int c2 = tid & 15;               // channel pair
            const int wc = hc ? (pxb + 128) : (pxb - 1);
            const int pz = hc ? 129 : 0;
            const int hz = h - 2 + rz;
            int d = 0;
            if (hz >= 0 && wc >= 0 && wc < W_) {
                const float a0 = xb[(size_t)(2*c2  )*HW_ + (size_t)hz*W_ + wc];
                const float a1 = xb[(size_t)(2*c2+1)*HW_ + (size_t)hz*W_ + wc];
                d = cvtpk(a0, a1);
            }
            ldsI[rz*ROWDW3 + pz*16 + c2] = d;
        }
    }
    __syncthreads();

    // ---- conv1: D1[o][px], bias pre-loaded into acc ------------------------
    f32x4 acc1[4][4];
    #pragma unroll
    for (int mt = 0; mt < 4; ++mt) {
        const f32x4 bv = *(const f32x4*)(b1 + mt*16 + 4*q);
        #pragma unroll
        for (int nt = 0; nt < 4; ++nt) acc1[mt][nt] = bv;
    }

    #pragma unroll
    for (int tap = 0; tap < 6; ++tap) {
        const int rb = (tap < 3) ? 0 : ROWB3;
        const int dw = (tap % 3) - 1;
        short8 wf[4];
        #pragma unroll
        for (int mt = 0; mt < 4; ++mt)
            wf[mt] = *(const short8*)(w1b + (mt*16 + lrow)*192 + tap*32 + q*8);
        #pragma unroll
        for (int nt = 0; nt < 4; ++nt) {
            const int p = wv*64 + nt*16 + lrow + dw + 1;    // halo-shifted, no clamp
            const int byteoff = rb + p*64 + ((q ^ ((p >> 2) & 3)) << 4);
            const short8 xf = *(const short8*)((const char*)ldsI + byteoff);
            #pragma unroll
            for (int mt = 0; mt < 4; ++mt)
                acc1[mt][nt] = __builtin_amdgcn_mfma_f32_16x16x32_bf16(
                                   wf[mt], xf, acc1[mt][nt], 0, 0, 0);
        }
    }

    // ---- ELU in-register ---------------------------------------------------
    #pragma unroll
    for (int mt = 0; mt < 4; ++mt)
        #pragma unroll
        for (int nt = 0; nt < 4; ++nt)
            #pragma unroll
            for (int rg = 0; rg < 4; ++rg) {
                const float v = acc1[mt][nt][rg];
                acc1[mt][nt][rg] = v > 0.f ? v : (__expf(v) - 1.f);
            }

    // ---- conv2: lane-local B-frags (hidden dim pre-permuted in w2b) -------
    short8 a2f[2][4];
    #pragma unroll
    for (int kt = 0; kt < 2; ++kt)
        #pragma unroll
        for (int mt2 = 0; mt2 < 4; ++mt2)
            a2f[kt][mt2] = *(const short8*)(w2b + (mt2*16 + lrow)*64 + kt*32 + q*8);

    f32x4 acc2[4][4];
    #pragma unroll
    for (int nt = 0; nt < 4; ++nt) {
        union { int4 i; short8 s; } u0, u1;
        u0.i.x = cvtpk(acc1[0][nt][0], acc1[0][nt][1]);
        u0.i.y = cvtpk(acc1[0][nt][2], acc1[0][nt][3]);
        u0.i.z = cvtpk(acc1[1][nt][0], acc1[1][nt][1]);
        u0.i.w = cvtpk(acc1[1][nt][2], acc1[1][nt][3]);
        u1.i.x = cvtpk(acc1[2][nt][0], acc1[2][nt][1]);
        u1.i.y = cvtpk(acc1[2][nt][2], acc1[2][nt][3]);
        u1.i.z = cvtpk(acc1[3][nt][0], acc1[3][nt][1]);
        u1.i.w = cvtpk(acc1[3][nt][2], acc1[3][nt][3]);
        #pragma unroll
        for (int mt2 = 0; mt2 < 4; ++mt2) {
            f32x4 t0 = __builtin_amdgcn_mfma_f32_16x16x32_bf16(
                           a2f[0][mt2], u0.s, (f32x4){0.f,0.f,0.f,0.f}, 0, 0, 0);
            acc2[mt2][nt] = __builtin_amdgcn_mfma_f32_16x16x32_bf16(
                           a2f[1][mt2], u1.s, t0, 0, 0, 0);
        }
    }

    // ---- epilogue: sigmoid/affine/logdet, all lane-local -------------------
    f32x4 b2m[2], b2s[2];
    #pragma unroll
    for (int mt2 = 0; mt2 < 2; ++mt2) {
        b2m[mt2] = *(const f32x4*)(b2 + mt2*16 + 4*q);
        b2s[mt2] = *(const f32x4*)(b2 + 32 + mt2*16 + 4*q);
    }

    float ldsum = 0.f;
    #pragma unroll
    for (int nt = 0; nt < 4; ++nt) {
        const int px = pxb + wv*64 + nt*16 + lrow;
        const int colbase = h*W_ + px;
        float pr8 = 1.f;                      // product of 8 scales -> one log
        #pragma unroll
        for (int mt2 = 0; mt2 < 2; ++mt2)
            #pragma unroll
            for (int rg = 0; rg < 4; ++rg) {
                const float mu = acc2[mt2][nt][rg]     + b2m[mt2][rg];
                const float z  = acc2[mt2 + 2][nt][rg] + b2s[mt2][rg] + 2.f;
                const float sc = 1.f / (1.f + __expf(-z));
                pr8 *= sc;
                const int j = mt2*16 + 4*q + rg;
                const size_t idx = (size_t)j * HW_ + colbase;
                ob[idx] = xb[idx] * sc + mu;
            }
        ldsum += __logf(pr8);
    }

    // ---- logdet partial: plain store, no atomic ----------------------------
    #pragma unroll
    for (int m = 32; m >= 1; m >>= 1) ldsum += __shfl_xor(ldsum, m, 64);
    if (l == 0) ldpart[(size_t)b * 1024 + rest * 2 + wv] = ldsum;
}

// ---------------------------------------------------------------------------
// Final reduce: 8 blocks, each sums 1024 partials -> logdet[b].
// ---------------------------------------------------------------------------
__global__ __launch_bounds__(256) void reduce_kernel(
    const float* __restrict__ ldpart, float* __restrict__ logdet)
{
    __shared__ float r4[4];
    const int b = blockIdx.x;
    const int t = threadIdx.x;
    const f32x4 v = *(const f32x4*)(ldpart + (size_t)b*1024 + t*4);
    float s = v[0] + v[1] + v[2] + v[3];
    #pragma unroll
    for (int m = 32; m >= 1; m >>= 1) s += __shfl_xor(s, m, 64);
    if ((t & 63) == 0) r4[t >> 6] = s;
    __syncthreads();
    if (t == 0) logdet[b] = r4[0] + r4[1] + r4[2] + r4[3];
}

// ---------------------------------------------------------------------------
extern "C" void kernel_launch(void* const* d_in, const int* in_sizes, int n_in,
                              void* d_out, int out_size, void* d_ws, size_t ws_size,
                              hipStream_t stream)
{
    const float* x  = (const float*)d_in[0];
    const float* v1 = (const float*)d_in[1];
    const float* g1 = (const float*)d_in[2];
    const float* b1 = (const float*)d_in[3];
    const float* v2 = (const float*)d_in[4];
    const float* g2 = (const float*)d_in[5];
    const float* b2 = (const float*)d_in[6];

    float* out    = (float*)d_out;
    float* logdet = out + NPIX;

    short* w1b    = (short*)d_ws;                    // 24576 B
    short* w2b    = w1b + 12288;                     //  8192 B
    float* ldpart = (float*)((char*)d_ws + 32768);   //  8192 f32 partials

    prep_kernel<<<128, 64, 0, stream>>>(v1, g1, v2, g2, w1b, w2b);
    flow_kernel<<<B_ * H_ * 2, 128, 0, stream>>>(x, w1b, w2b, b1, b2, out, ldpart);
    reduce_kernel<<<B_, 256, 0, stream>>>(ldpart, logdet);
}